// Round 1
// baseline (152.067 us; speedup 1.0000x reference)
//
#include <hip/hip_runtime.h>
#include <hip/hip_bf16.h>
#include <math.h>

// Problem constants
constexpr int L = 4096;   // seq len
constexpr int D = 1024;   // d_model
constexpr int N = 16;     // hiddens per channel
constexpr int NC = 32;    // chunks
constexpr int T = L / NC; // 128 steps per chunk

// softplus, numerically stable
__device__ __forceinline__ float softplus_f(float v) {
    return fmaxf(v, 0.0f) + log1pf(expf(-fabsf(v)));
}

// Kernel 1: per (chunk, d, n) local scan with zero init in g-space:
//   g = Lam * g + x   (x real)
// store end state s[c][d*N+n].
__global__ __launch_bounds__(256) void k_local(
    const float* __restrict__ x,
    const float* __restrict__ Delta,
    const float* __restrict__ A_re,
    const float* __restrict__ A_im,
    float2* __restrict__ s)
{
    int tid = blockIdx.x * 256 + threadIdx.x;   // c*(D*N) + d*N + n
    int n = tid & (N - 1);
    int d = (tid >> 4) & (D - 1);
    int c = tid >> 14;                           // D*N = 16384 = 2^14

    float dt = softplus_f(Delta[d]);
    int idx = d * N + n;
    float ar = A_re[idx] * dt;
    float ai = A_im[idx] * dt;
    float e  = expf(ar);
    float Lr = e * cosf(ai);
    float Li = e * sinf(ai);

    float gr = 0.0f, gi = 0.0f;
    const float* xp = x + c * T * D + d;
    #pragma unroll 8
    for (int i = 0; i < T; ++i) {
        float xv = xp[i * D];
        float t  = fmaf(-Li, gi, xv);
        float nr = fmaf(Lr, gr, t);          // gr' = Lr*gr - Li*gi + x
        gi = fmaf(Lr, gi, Li * gr);          // gi' = Lr*gi + Li*gr (old gr)
        gr = nr;
    }
    s[tid] = make_float2(gr, gi);
}

// Kernel 2: per (d,n) sequential scan over the NC chunk summaries.
// In-place: s[c] (local end state) -> carry-in for chunk c (state before chunk c).
//   carry[c] = acc;  acc = Lam^T * acc + s[c]
__global__ __launch_bounds__(256) void k_scan(
    const float* __restrict__ Delta,
    const float* __restrict__ A_re,
    const float* __restrict__ A_im,
    float2* __restrict__ s)
{
    int tid = blockIdx.x * 256 + threadIdx.x;   // d*N + n, 16384 threads
    int n = tid & (N - 1);
    int d = tid >> 4;

    float dt = softplus_f(Delta[d]);
    int idx = d * N + n;
    float ar = A_re[idx] * dt;
    float ai = A_im[idx] * dt;
    float e  = expf(ar);
    float Lr = e * cosf(ai);
    float Li = e * sinf(ai);
    // Lam^T via repeated squaring: T = 128 = 2^7
    #pragma unroll
    for (int k = 0; k < 7; ++k) {
        float a = Lr, b = Li;
        Lr = a * a - b * b;
        Li = 2.0f * a * b;
    }

    float cr = 0.0f, ci = 0.0f;
    #pragma unroll
    for (int c = 0; c < NC; ++c) {
        float2 sv = s[c * (D * N) + tid];
        s[c * (D * N) + tid] = make_float2(cr, ci);
        float nr = fmaf(Lr, cr, fmaf(-Li, ci, sv.x));
        ci = fmaf(Lr, ci, fmaf(Li, cr, sv.y));
        cr = nr;
    }
}

// Kernel 3: recompute scan per chunk with correct carry, contract with
// C' = dt*B*C over n (4 n per thread, reduce over 4 lanes), add D*x, store.
__global__ __launch_bounds__(256) void k_out(
    const float* __restrict__ x,
    const float* __restrict__ Delta,
    const float* __restrict__ A_re,
    const float* __restrict__ A_im,
    const float* __restrict__ B_re,
    const float* __restrict__ B_im,
    const float* __restrict__ C_re,
    const float* __restrict__ C_im,
    const float* __restrict__ Dp,
    const float2* __restrict__ carry,
    float* __restrict__ out)
{
    int tid = blockIdx.x * 256 + threadIdx.x;   // c*(D*4) + d*4 + q
    int q = tid & 3;
    int d = (tid >> 2) & (D - 1);
    int c = tid >> 12;                           // D*4 = 4096 = 2^12

    float dt = softplus_f(Delta[d]);

    float Lr[4], Li[4], Cr[4], Ci[4], gr[4], gi[4];
    #pragma unroll
    for (int j = 0; j < 4; ++j) {
        int n = q * 4 + j;
        int idx = d * N + n;
        float ar = A_re[idx] * dt;
        float ai = A_im[idx] * dt;
        float e  = expf(ar);
        Lr[j] = e * cosf(ai);
        Li[j] = e * sinf(ai);
        // C' = dt * (C * B)  (complex mul)
        float br = B_re[idx], bi = B_im[idx];
        float cre = C_re[idx], cim = C_im[idx];
        Cr[j] = dt * (cre * br - cim * bi);
        Ci[j] = dt * (cre * bi + cim * br);
        float2 cv = carry[c * (D * N) + idx];
        gr[j] = cv.x;
        gi[j] = cv.y;
    }
    float dpv = Dp[d];

    const float* xp = x + c * T * D + d;
    float*       op = out + c * T * D + d;

    for (int i = 0; i < T; ++i) {
        float xv = xp[i * D];
        float acc = 0.0f;
        #pragma unroll
        for (int j = 0; j < 4; ++j) {
            float t  = fmaf(-Li[j], gi[j], xv);
            float nr = fmaf(Lr[j], gr[j], t);
            gi[j] = fmaf(Lr[j], gi[j], Li[j] * gr[j]);
            gr[j] = nr;
            acc = fmaf(Cr[j], gr[j], acc);
            acc = fmaf(-Ci[j], gi[j], acc);
        }
        acc += __shfl_xor(acc, 1);
        acc += __shfl_xor(acc, 2);
        if (q == 0) op[i * D] = fmaf(dpv, xv, acc);
    }
}

extern "C" void kernel_launch(void* const* d_in, const int* in_sizes, int n_in,
                              void* d_out, int out_size, void* d_ws, size_t ws_size,
                              hipStream_t stream) {
    const float* x     = (const float*)d_in[0];
    const float* Delta = (const float*)d_in[1];
    const float* A_re  = (const float*)d_in[2];
    const float* A_im  = (const float*)d_in[3];
    const float* B_re  = (const float*)d_in[4];
    const float* B_im  = (const float*)d_in[5];
    const float* C_re  = (const float*)d_in[6];
    const float* C_im  = (const float*)d_in[7];
    const float* Dp    = (const float*)d_in[8];
    float* out = (float*)d_out;
    float2* s  = (float2*)d_ws;   // NC * D * N float2 = 4 MiB

    // K1: local chunk scans. NC*D*N threads.
    k_local<<<(NC * D * N) / 256, 256, 0, stream>>>(x, Delta, A_re, A_im, s);
    // K2: chunk-level scan. D*N threads.
    k_scan<<<(D * N) / 256, 256, 0, stream>>>(Delta, A_re, A_im, s);
    // K3: recompute + output. NC*D*4 threads.
    k_out<<<(NC * D * 4) / 256, 256, 0, stream>>>(x, Delta, A_re, A_im,
                                                  B_re, B_im, C_re, C_im, Dp,
                                                  s, out);
}

// Round 2
// 132.559 us; speedup vs baseline: 1.1472x; 1.1472x over previous
//
#include <hip/hip_runtime.h>
#include <hip/hip_bf16.h>
#include <math.h>

// Problem constants
constexpr int L = 4096;   // seq len
constexpr int D = 1024;   // d_model
constexpr int N = 16;     // hiddens per channel

// softplus, numerically stable
__device__ __forceinline__ float softplus_f(float v) {
    return fmaxf(v, 0.0f) + log1pf(expf(-fabsf(v)));
}

constexpr int ilog2(int v) { return v == 1 ? 0 : 1 + ilog2(v / 2); }

// Kernel 1: per (chunk, d, n) local scan with zero init in g-space:
//   g = Lam * g + x   (x real)
// store end state s[c][d*N+n].
template<int NC>
__global__ __launch_bounds__(256) void k_local(
    const float* __restrict__ x,
    const float* __restrict__ Delta,
    const float* __restrict__ A_re,
    const float* __restrict__ A_im,
    float2* __restrict__ s)
{
    constexpr int T = L / NC;
    int tid = blockIdx.x * 256 + threadIdx.x;   // c*(D*N) + d*N + n
    int d = (tid >> 4) & (D - 1);
    int c = tid >> 14;                           // D*N = 16384 = 2^14

    float dt = softplus_f(Delta[d]);
    int idx = tid & (D * N - 1);
    float ar = A_re[idx] * dt;
    float ai = A_im[idx] * dt;
    float e  = expf(ar);
    float Lr = e * cosf(ai);
    float Li = e * sinf(ai);

    float gr = 0.0f, gi = 0.0f;
    const float* xp = x + c * T * D + d;
    for (int i0 = 0; i0 < T; i0 += 8) {
        float xv[8];
        #pragma unroll
        for (int u = 0; u < 8; ++u) xv[u] = xp[(i0 + u) * D];
        #pragma unroll
        for (int u = 0; u < 8; ++u) {
            float t  = fmaf(-Li, gi, xv[u]);
            float nr = fmaf(Lr, gr, t);          // gr' = Lr*gr - Li*gi + x
            gi = fmaf(Lr, gi, Li * gr);          // gi' = Lr*gi + Li*gr (old gr)
            gr = nr;
        }
    }
    s[tid] = make_float2(gr, gi);
}

// Kernel 2: per (d,n) sequential scan over the NC chunk summaries.
// In-place: s[c] (local end state) -> carry-in for chunk c (state before chunk c).
template<int NC>
__global__ __launch_bounds__(256) void k_scan(
    const float* __restrict__ Delta,
    const float* __restrict__ A_re,
    const float* __restrict__ A_im,
    float2* __restrict__ s)
{
    constexpr int T = L / NC;
    int tid = blockIdx.x * 256 + threadIdx.x;   // d*N + n, 16384 threads
    int d = tid >> 4;

    float dt = softplus_f(Delta[d]);
    float ar = A_re[tid] * dt;
    float ai = A_im[tid] * dt;
    float e  = expf(ar);
    float Lr = e * cosf(ai);
    float Li = e * sinf(ai);
    // Lam^T via repeated squaring
    #pragma unroll
    for (int k = 0; k < ilog2(T); ++k) {
        float a = Lr, b = Li;
        Lr = a * a - b * b;
        Li = 2.0f * a * b;
    }

    float cr = 0.0f, ci = 0.0f;
    #pragma unroll
    for (int c0 = 0; c0 < NC; c0 += 8) {
        float2 sv[8];
        #pragma unroll
        for (int u = 0; u < 8; ++u) sv[u] = s[(c0 + u) * (D * N) + tid];
        #pragma unroll
        for (int u = 0; u < 8; ++u) {
            s[(c0 + u) * (D * N) + tid] = make_float2(cr, ci);
            float nr = fmaf(Lr, cr, fmaf(-Li, ci, sv[u].x));
            ci = fmaf(Lr, ci, fmaf(Li, cr, sv[u].y));
            cr = nr;
        }
    }
}

// Kernel 3: recompute scan per chunk with correct carry, contract with
// C' = dt*B*C over n (4 n per thread, reduce over 4 lanes), add D*x, store.
template<int NC>
__global__ __launch_bounds__(256) void k_out(
    const float* __restrict__ x,
    const float* __restrict__ Delta,
    const float* __restrict__ A_re,
    const float* __restrict__ A_im,
    const float* __restrict__ B_re,
    const float* __restrict__ B_im,
    const float* __restrict__ C_re,
    const float* __restrict__ C_im,
    const float* __restrict__ Dp,
    const float2* __restrict__ carry,
    float* __restrict__ out)
{
    constexpr int T = L / NC;
    int tid = blockIdx.x * 256 + threadIdx.x;   // c*(D*4) + d*4 + q
    int q = tid & 3;
    int d = (tid >> 2) & (D - 1);
    int c = tid >> 12;                           // D*4 = 4096 = 2^12

    float dt = softplus_f(Delta[d]);

    float Lr[4], Li[4], Cr[4], Ci[4], gr[4], gi[4];
    #pragma unroll
    for (int j = 0; j < 4; ++j) {
        int n = q * 4 + j;
        int idx = d * N + n;
        float ar = A_re[idx] * dt;
        float ai = A_im[idx] * dt;
        float e  = expf(ar);
        Lr[j] = e * cosf(ai);
        Li[j] = e * sinf(ai);
        // C' = dt * (C * B)  (complex mul)
        float br = B_re[idx], bi = B_im[idx];
        float cre = C_re[idx], cim = C_im[idx];
        Cr[j] = dt * (cre * br - cim * bi);
        Ci[j] = dt * (cre * bi + cim * br);
        float2 cv = carry[c * (D * N) + idx];
        gr[j] = cv.x;
        gi[j] = cv.y;
    }
    float dpv = Dp[d];

    const float* xp = x + c * T * D + d;
    float*       op = out + c * T * D + d;

    for (int i0 = 0; i0 < T; i0 += 8) {
        float xv[8];
        #pragma unroll
        for (int u = 0; u < 8; ++u) xv[u] = xp[(i0 + u) * D];
        #pragma unroll
        for (int u = 0; u < 8; ++u) {
            float acc = 0.0f;
            #pragma unroll
            for (int j = 0; j < 4; ++j) {
                float t  = fmaf(-Li[j], gi[j], xv[u]);
                float nr = fmaf(Lr[j], gr[j], t);
                gi[j] = fmaf(Lr[j], gi[j], Li[j] * gr[j]);
                gr[j] = nr;
                acc = fmaf(Cr[j], gr[j], acc);
                acc = fmaf(-Ci[j], gi[j], acc);
            }
            acc += __shfl_xor(acc, 1);
            acc += __shfl_xor(acc, 2);
            if (q == 0) op[(i0 + u) * D] = fmaf(dpv, xv[u], acc);
        }
    }
}

template<int NC>
static void launch_all(const float* x, const float* Delta,
                       const float* A_re, const float* A_im,
                       const float* B_re, const float* B_im,
                       const float* C_re, const float* C_im,
                       const float* Dp, float* out, float2* s,
                       hipStream_t stream)
{
    k_local<NC><<<(NC * D * N) / 256, 256, 0, stream>>>(x, Delta, A_re, A_im, s);
    k_scan<NC><<<(D * N) / 256, 256, 0, stream>>>(Delta, A_re, A_im, s);
    k_out<NC><<<(NC * D * 4) / 256, 256, 0, stream>>>(x, Delta, A_re, A_im,
                                                      B_re, B_im, C_re, C_im, Dp,
                                                      s, out);
}

extern "C" void kernel_launch(void* const* d_in, const int* in_sizes, int n_in,
                              void* d_out, int out_size, void* d_ws, size_t ws_size,
                              hipStream_t stream) {
    const float* x     = (const float*)d_in[0];
    const float* Delta = (const float*)d_in[1];
    const float* A_re  = (const float*)d_in[2];
    const float* A_im  = (const float*)d_in[3];
    const float* B_re  = (const float*)d_in[4];
    const float* B_im  = (const float*)d_in[5];
    const float* C_re  = (const float*)d_in[6];
    const float* C_im  = (const float*)d_in[7];
    const float* Dp    = (const float*)d_in[8];
    float* out = (float*)d_out;
    float2* s  = (float2*)d_ws;   // NC * D * N * sizeof(float2)

    size_t need128 = (size_t)128 * D * N * sizeof(float2); // 16 MiB
    size_t need64  = (size_t)64  * D * N * sizeof(float2); //  8 MiB
    if (ws_size >= need128)
        launch_all<128>(x, Delta, A_re, A_im, B_re, B_im, C_re, C_im, Dp, out, s, stream);
    else if (ws_size >= need64)
        launch_all<64>(x, Delta, A_re, A_im, B_re, B_im, C_re, C_im, Dp, out, s, stream);
    else
        launch_all<32>(x, Delta, A_re, A_im, B_re, B_im, C_re, C_im, Dp, out, s, stream);
}